// Round 12
// baseline (2813.577 us; speedup 1.0000x reference)
//
#include <hip/hip_runtime.h>
#include <stdint.h>

typedef __attribute__((ext_vector_type(4))) float f32x4;
typedef __attribute__((ext_vector_type(2))) long lx2;
typedef unsigned short u16;
typedef unsigned char u8;

#define MFMA8(a,b,c) __builtin_amdgcn_mfma_f32_16x16x32_fp8_fp8((a),(b),(c),0,0,0)

static constexpr int T_STEPS = 256;
static constexpr int BATCH   = 2048;
static constexpr int YDIM    = 20;
static constexpr int BS      = 16;
static constexpr int NWG     = BATCH / BS;        // 128

// fp8 ws layout IDENTICAL to R10/R11 (proven, absmax 0): 768 pairs x 1KB = 24
// chunks x 32KB. Pair P, lane L, half h, j: byte P*1024+L*16+h*8+j = W[row][k],
// k = kb*32 + (L>>4)*8 + j. Consuming wave = P mod 8.
// Residency (new): old chunks 0-2 (whh0 kb0-3) + chunk 6 (wih0) -> LDS once;
// old chunks 19-23 (W1,W2,W3) -> VGPRs once. Streamed per step: old chunks
// {3,4,5, 7..12, 13..18} = 15 x 32KB = 480 KB.
static constexpr int NPAIR   = 768;
static constexpr int WS_U16  = NPAIR * 512;       // 768 KB

__device__ __forceinline__ float sigm(float x) { return 1.0f / (1.0f + __expf(-x)); }
__device__ __forceinline__ float tanh_fast(float x) {
    float s = __expf(-2.0f * fabsf(x));
    float r = (1.0f - s) / (1.0f + s);
    return copysignf(r, x);
}
__device__ __forceinline__ f32x4 zero4() { f32x4 v = {0.f,0.f,0.f,0.f}; return v; }
__device__ __forceinline__ u8 f2f8(float v) {
    return (u8)(__builtin_amdgcn_cvt_pk_fp8_f32(v, v, 0, false) & 0xff);
}
__device__ __forceinline__ void pinv(lx2& v) { asm volatile("" : "+v"(v)); }

__device__ float sval(int P, int half, int l16, int k8,
                      const float* __restrict__ Wih0, const float* __restrict__ Whh0,
                      const float* __restrict__ Wih1, const float* __restrict__ Whh1,
                      const float* __restrict__ W1,   const float* __restrict__ W2,
                      const float* __restrict__ W3) {
    if (P < 192) { int kb=P/24, r=P%24, g=r>>3, wv=r&7, c=wv+8*half;
        return Whh0[(g*256 + c*16 + l16)*256 + kb*32 + k8]; }
    if (P < 224) { int r=P-192; if (r>=24) return 0.f;
        int g=r>>3, wv=r&7, c=wv+8*half, row=g*256+c*16+l16;
        return (k8 < YDIM) ? Wih0[row*YDIM + k8] : 0.f; }
    if (P < 416) { int r=P-224, kb=r/24, rr=r%24, g=rr>>3, wv=rr&7, c=wv+8*half;
        return Whh1[(g*256 + c*16 + l16)*256 + kb*32 + k8]; }
    if (P < 608) { int r=P-416, kb=r/24, rr=r%24, g=rr>>3, wv=rr&7, c=wv+8*half;
        return Wih1[(g*256 + c*16 + l16)*256 + kb*32 + k8]; }
    if (P < 672) { int r=P-608, kb=r>>3, wv=r&7, row=(wv+8*half)*16+l16;
        return W1[row*256 + kb*32 + k8]; }
    if (P < 736) { int r=P-672, kb=r>>3, wv=r&7, row=(wv+8*half)*16+l16;
        return W2[row*256 + kb*32 + k8]; }
    { int r=P-736, s=r>>3, wv=r&7;
      if (wv < 2) { int kb = 2*s + half, row = wv*16 + l16;
          return (row < YDIM) ? W3[row*256 + kb*32 + k8] : 0.f; }
      return 0.f; }
}

__global__ void prep_kernel(const float* __restrict__ Wih0, const float* __restrict__ Whh0,
                            const float* __restrict__ Wih1, const float* __restrict__ Whh1,
                            const float* __restrict__ W1,   const float* __restrict__ W2,
                            const float* __restrict__ W3,   u16* __restrict__ ws,
                            float* __restrict__ out) {
    int tid = blockIdx.x * blockDim.x + threadIdx.x;
    if (tid == 0) out[0] = 0.0f;
    int stride = gridDim.x * blockDim.x;
    for (int m = tid; m < WS_U16; m += stride) {
        int byte0 = 2 * m;
        int P = byte0 >> 10, rem = byte0 & 1023;
        int L = rem >> 4, half = (rem >> 3) & 1, j0 = rem & 7;
        int l16 = L & 15, kqb = (L >> 4) * 8;
        float v0 = sval(P, half, l16, kqb + j0,     Wih0, Whh0, Wih1, Whh1, W1, W2, W3);
        float v1 = sval(P, half, l16, kqb + j0 + 1, Wih0, Whh0, Wih1, Whh1, W1, W2, W3);
        ws[m] = (u16)(__builtin_amdgcn_cvt_pk_fp8_f32(v0, v1, 0, false) & 0xffff);
    }
}

#define BARX() do {                                                 \
    asm volatile("s_waitcnt lgkmcnt(0)" ::: "memory");              \
    __builtin_amdgcn_sched_barrier(0);                              \
    __builtin_amdgcn_s_barrier();                                   \
    __builtin_amdgcn_sched_barrier(0);                              \
} while (0)

#define GM2(ACC, A, PV) do { ACC[0] = MFMA8((A), (PV).x, ACC[0]);   \
                             ACC[1] = MFMA8((A), (PV).y, ACC[1]); } while (0)
#define AFB(S, KT) (*(const long*)&(S)[l16][(KT) * 32 + kq8])
#define LOADC(R0, R1, R2, R3, C) do {                               \
    const u8* b_ = wsl + (size_t)(C) * 32768 + woff;                \
    R0 = *(const lx2*)(b_);          R1 = *(const lx2*)(b_ + 8192); \
    R2 = *(const lx2*)(b_ + 16384); R3 = *(const lx2*)(b_ + 24576); \
} while (0)
// LDS-resident pair read (same 1KB-pair geometry as the stream)
#define LP(BASE, P) (*(const lx2*)&(BASE)[(size_t)(P) * 1024 + (size_t)lane * 16])
// chunk MFMA gate interleaves (R10/R11-verified)
#define XCH_A(P0,P1,P2,P3, S, KB, AR,AZ,AN) do {                    \
    const long a0_ = AFB(S, KB), a1_ = AFB(S, (KB)+1);              \
    GM2(AR,a0_,P0); GM2(AZ,a0_,P1); GM2(AN,a0_,P2); GM2(AR,a1_,P3); } while (0)
#define XCH_B(P0,P1,P2,P3, S, KB, AR,AZ,AN) do {                    \
    const long a0_ = AFB(S, KB), a1_ = AFB(S, (KB)+1);              \
    GM2(AZ,a0_,P0); GM2(AN,a0_,P1); GM2(AR,a1_,P2); GM2(AZ,a1_,P3); } while (0)
#define XCH_C(P0,P1,P2,P3, S, KB, AR,AZ,AN) do {                    \
    const long a0_ = AFB(S, KB), a1_ = AFB(S, (KB)+1);              \
    GM2(AN,a0_,P0); GM2(AR,a1_,P1); GM2(AZ,a1_,P2); GM2(AN,a1_,P3); } while (0)
#define XCH_M(P0,P1,P2,P3, S, KB0) do {                             \
    const long m0_ = AFB(S, KB0),     m1_ = AFB(S, (KB0)+1);        \
    const long m2_ = AFB(S, (KB0)+2), m3_ = AFB(S, (KB0)+3);        \
    d0 = MFMA8(m0_, P0.x, d0);  d1v = MFMA8(m0_, P0.y, d1v);        \
    d0 = MFMA8(m1_, P1.x, d0);  d1v = MFMA8(m1_, P1.y, d1v);        \
    d0 = MFMA8(m2_, P2.x, d0);  d1v = MFMA8(m2_, P2.y, d1v);        \
    d0 = MFMA8(m3_, P3.x, d0);  d1v = MFMA8(m3_, P3.y, d1v);        \
} while (0)
#define COMBINE(HSH, HR, BRv, BZv, BXNv, BHNv, AR, AZ, AXN, AHN) do {            \
    _Pragma("unroll") for (int jj = 0; jj < 2; ++jj) {                           \
        const int colb_ = (w + 8 * jj) * 16 + l16;                               \
        _Pragma("unroll") for (int q = 0; q < 4; ++q) {                          \
            const float r_ = sigm(AR[jj][q] + BRv[jj]);                          \
            const float z_ = sigm(AZ[jj][q] + BZv[jj]);                          \
            const float n_ = tanh_fast(AXN[jj][q] + BXNv[jj] + r_ * (AHN[jj][q] + BHNv[jj])); \
            const float hn_ = (1.0f - z_) * n_ + z_ * HR[jj][q];                 \
            HR[jj][q] = hn_;                                                     \
            HSH[kq * 4 + q][colb_] = f2f8(hn_); } }                              \
} while (0)
#define DWRITE(DSH, SB) do {                                                     \
    _Pragma("unroll") for (int q = 0; q < 4; ++q) {                              \
        DSH[kq * 4 + q][w * 16 + l16]       = f2f8(fmaxf(d0[q]  + SB[0], 0.f));  \
        DSH[kq * 4 + q][(8 + w) * 16 + l16] = f2f8(fmaxf(d1v[q] + SB[1], 0.f)); }\
} while (0)
#define ZACC(A) do { A[0] = zero4(); A[1] = zero4(); } while (0)

__global__ __launch_bounds__(512, 1) void rnn_main(
    const float* __restrict__ data,
    const float* __restrict__ bih0g, const float* __restrict__ bhh0g,
    const float* __restrict__ bih1g, const float* __restrict__ bhh1g,
    const float* __restrict__ b1g,  const float* __restrict__ b2g,
    const float* __restrict__ b3g,
    const u16* __restrict__ ws, float* __restrict__ out)
{
    __shared__ __align__(16) u8 lds_whh0[3 * 32768];  // old chunks 0-2 (whh0 kb0-3)
    __shared__ __align__(16) u8 lds_wih0[32768];      // old chunk 6 (wih0)
    __shared__ __align__(16) u8 sh_h0[2][16][272];
    __shared__ __align__(16) u8 sh_h1[2][16][272];
    __shared__ __align__(16) u8 sh_d1[16][272];
    __shared__ __align__(16) u8 sh_d2[16][272];
    __shared__ __align__(16) u8 sh_x[16][32];

    const int tid  = threadIdx.x;
    const int w    = tid >> 6;
    const int lane = tid & 63;
    const int l16  = lane & 15;
    const int kq   = lane >> 4;
    const int kq8  = kq * 8;
    const int b0   = blockIdx.x * BS;
    const int xr   = tid / YDIM, xc = tid - xr * YDIM;
    const size_t woff = (size_t)w * 1024 + (size_t)lane * 16;

    // ---- one-time: LDS-resident weights ----
    {
        const lx2* s = (const lx2*)ws;
        lx2* dW = (lx2*)lds_whh0;
        lx2* dX = (lx2*)lds_wih0;
        for (int i = tid; i < 6144; i += 512) dW[i] = s[i];            // chunks 0-2
        for (int i = tid; i < 2048; i += 512) dX[i] = s[12288 + i];    // chunk 6
    }
    // ---- one-time: VGPR-resident W1/W2/W3 ----
    lx2 w1r[8], w2r[8], w3r[4];
    {
        const u8* b = (const u8*)ws;
        #pragma unroll
        for (int s = 0; s < 4; ++s) {
            w1r[s]     = *(const lx2*)(b + (size_t)((19*32 + s*8 + w)) * 1024 + (size_t)lane * 16);
            w1r[4 + s] = *(const lx2*)(b + (size_t)((20*32 + s*8 + w)) * 1024 + (size_t)lane * 16);
            w2r[s]     = *(const lx2*)(b + (size_t)((21*32 + s*8 + w)) * 1024 + (size_t)lane * 16);
            w2r[4 + s] = *(const lx2*)(b + (size_t)((22*32 + s*8 + w)) * 1024 + (size_t)lane * 16);
            w3r[s]     = *(const lx2*)(b + (size_t)((23*32 + s*8 + w)) * 1024 + (size_t)lane * 16);
        }
        #pragma unroll
        for (int s = 0; s < 4; ++s) { pinv(w1r[s]); pinv(w1r[4+s]); pinv(w2r[s]); pinv(w2r[4+s]); pinv(w3r[s]); }
    }

    for (int i = tid; i < 2 * 16 * 272; i += 512) { (&sh_h0[0][0][0])[i] = 0; (&sh_h1[0][0][0])[i] = 0; }
    for (int i = tid; i < 16 * 32;  i += 512) (&sh_x[0][0])[i] = 0;
    if (tid < BS * YDIM) sh_x[xr][xc] = f2f8(data[(size_t)b0 * YDIM + tid]);

    float bR0[2], bZ0[2], bXN0[2], bHN0[2], bR1[2], bZ1[2], bXN1[2], bHN1[2], s1r[2], s2r[2];
    #pragma unroll
    for (int jj = 0; jj < 2; ++jj) {
        const int colb = (w + 8 * jj) * 16 + l16;
        bR0[jj]  = bih0g[colb] + bhh0g[colb];
        bZ0[jj]  = bih0g[colb + 256] + bhh0g[colb + 256];
        bXN0[jj] = bih0g[colb + 512];  bHN0[jj] = bhh0g[colb + 512];
        bR1[jj]  = bih1g[colb] + bhh1g[colb];
        bZ1[jj]  = bih1g[colb + 256] + bhh1g[colb + 256];
        bXN1[jj] = bih1g[colb + 512];  bHN1[jj] = bhh1g[colb + 512];
        s1r[jj]  = b1g[colb];  s2r[jj] = b2g[colb];
    }
    float s3r = 0.0f;
    { const int col = w * 16 + l16; if (w < 2 && col < YDIM) s3r = b3g[col]; }

    float hr0[2][4] = {{0,0,0,0},{0,0,0,0}};
    float hr1[2][4] = {{0,0,0,0},{0,0,0,0}};
    f32x4 r0[2], z0[2], xn0[2], hn0[2];
    f32x4 r1[2], z1[2], xn1[2], hn1[2];
    f32x4 d0, d1v;
    lx2 p00, p01, p02, p03, p10, p11, p12, p13, p20, p21, p22, p23;

    __syncthreads();   // LDS residents + state ready

    {   // prologue: prime 3-deep register ring with stream idx 0,1,2 (old chunks 3,4,5)
        const u8* wsl = (const u8*)ws;
        LOADC(p00, p01, p02, p03, 3);
        LOADC(p10, p11, p12, p13, 4);
        LOADC(p20, p21, p22, p23, 5);
    }
    float loss = 0.0f;

    #pragma unroll 1
    for (int t = 0; t < T_STEPS - 1; ++t) {
        const u8* wsl = (const u8*)ws;
        asm volatile("" : "+s"(wsl));     // defeat LICM on stream loads
        u8 (*h0o)[272] = sh_h0[t & 1];  u8 (*h0n)[272] = sh_h0[(t & 1) ^ 1];
        u8 (*h1o)[272] = sh_h1[t & 1];  u8 (*h1n)[272] = sh_h1[(t & 1) ^ 1];

        ZACC(r0); ZACC(z0); ZACC(xn0); ZACC(hn0);
        ZACC(r1); ZACC(z1); ZACC(xn1); ZACC(hn1);

        // ===== Phase A: gh0 (kb0-3 from LDS, kb4-7 from stream) + gx0 (LDS) + gh1 (stream) =====
        {   lx2 q0=LP(lds_whh0, w),      q1=LP(lds_whh0, 8+w),  q2=LP(lds_whh0, 16+w), q3=LP(lds_whh0, 24+w);
            XCH_A(q0,q1,q2,q3, h0o, 0, r0,z0,hn0); }
        {   lx2 q0=LP(lds_whh0, 32+w),   q1=LP(lds_whh0, 40+w), q2=LP(lds_whh0, 48+w), q3=LP(lds_whh0, 56+w);
            XCH_B(q0,q1,q2,q3, h0o, 1, r0,z0,hn0); }
        {   lx2 q0=LP(lds_whh0, 64+w),   q1=LP(lds_whh0, 72+w), q2=LP(lds_whh0, 80+w), q3=LP(lds_whh0, 88+w);
            XCH_C(q0,q1,q2,q3, h0o, 2, r0,z0,hn0); }
        XCH_A(p00,p01,p02,p03, h0o, 4, r0,z0,hn0);  LOADC(p00,p01,p02,p03, 7);
        XCH_B(p10,p11,p12,p13, h0o, 5, r0,z0,hn0);  LOADC(p10,p11,p12,p13, 8);
        XCH_C(p20,p21,p22,p23, h0o, 6, r0,z0,hn0);  LOADC(p20,p21,p22,p23, 9);
        {   // gx0 from LDS-resident wih0
            const long ax = *(const long*)&sh_x[l16][kq8];
            lx2 q0=LP(lds_wih0, w), q1=LP(lds_wih0, 8+w), q2=LP(lds_wih0, 16+w);
            GM2(r0, ax, q0); GM2(z0, ax, q1); GM2(xn0, ax, q2);
        }
        XCH_A(p00,p01,p02,p03, h1o, 0, r1,z1,hn1);  LOADC(p00,p01,p02,p03, 10);
        XCH_B(p10,p11,p12,p13, h1o, 1, r1,z1,hn1);  LOADC(p10,p11,p12,p13, 11);
        XCH_C(p20,p21,p22,p23, h1o, 2, r1,z1,hn1);  LOADC(p20,p21,p22,p23, 12);
        XCH_A(p00,p01,p02,p03, h1o, 4, r1,z1,hn1);  LOADC(p00,p01,p02,p03, 13);
        XCH_B(p10,p11,p12,p13, h1o, 5, r1,z1,hn1);  LOADC(p10,p11,p12,p13, 14);
        XCH_C(p20,p21,p22,p23, h1o, 6, r1,z1,hn1);  LOADC(p20,p21,p22,p23, 15);
        COMBINE(h0n, hr0, bR0, bZ0, bXN0, bHN0, r0, z0, xn0, hn0);
        BARX();                                  // publish h0new
        // ===== Phase C: gx1 = wih1 @ h0new (stream) =====
        XCH_A(p00,p01,p02,p03, h0n, 0, r1,z1,xn1);  LOADC(p00,p01,p02,p03, 16);
        XCH_B(p10,p11,p12,p13, h0n, 1, r1,z1,xn1);  LOADC(p10,p11,p12,p13, 17);
        XCH_C(p20,p21,p22,p23, h0n, 2, r1,z1,xn1);  LOADC(p20,p21,p22,p23, 18);
        XCH_A(p00,p01,p02,p03, h0n, 4, r1,z1,xn1);  LOADC(p00,p01,p02,p03, 3);
        XCH_B(p10,p11,p12,p13, h0n, 5, r1,z1,xn1);  LOADC(p10,p11,p12,p13, 4);
        XCH_C(p20,p21,p22,p23, h0n, 6, r1,z1,xn1);  LOADC(p20,p21,p22,p23, 5);
        COMBINE(h1n, hr1, bR1, bZ1, bXN1, bHN1, r1, z1, xn1, hn1);
        BARX();                                  // publish h1new
        // ===== Phase D: W1 (VGPR-resident); x(t+1)/targets to regs =====
        d0 = zero4(); d1v = zero4();
        float xv = 0.f, tg0 = 0.f, tg1 = 0.f, tg2 = 0.f, tg3 = 0.f;
        {
            const float* tp = data + (size_t)(t + 1) * (BATCH * YDIM) + (size_t)b0 * YDIM;
            if (tid < BS * YDIM) xv = tp[tid];
            if (w < 2) {
                const int col = w * 16 + l16;
                if (col < YDIM) {
                    tg0 = tp[(kq * 4 + 0) * YDIM + col];
                    tg1 = tp[(kq * 4 + 1) * YDIM + col];
                    tg2 = tp[(kq * 4 + 2) * YDIM + col];
                    tg3 = tp[(kq * 4 + 3) * YDIM + col];
                }
            }
        }
        XCH_M(w1r[0], w1r[1], w1r[2], w1r[3], h1n, 0);
        XCH_M(w1r[4], w1r[5], w1r[6], w1r[7], h1n, 4);
        DWRITE(sh_d1, s1r);
        BARX();                                  // publish d1
        // ===== Phase E: W2 (VGPR-resident) =====
        d0 = zero4(); d1v = zero4();
        XCH_M(w2r[0], w2r[1], w2r[2], w2r[3], sh_d1, 0);
        XCH_M(w2r[4], w2r[5], w2r[6], w2r[7], sh_d1, 4);
        DWRITE(sh_d2, s2r);
        BARX();                                  // publish d2
        // ===== Phase F: W3 (VGPR-resident) + loss (waves 0,1); stage x(t+1) =====
        if (w < 2) {
            f32x4 lacc = zero4();
            lacc = MFMA8(AFB(sh_d2, 0), w3r[0].x, lacc);
            lacc = MFMA8(AFB(sh_d2, 1), w3r[0].y, lacc);
            lacc = MFMA8(AFB(sh_d2, 2), w3r[1].x, lacc);
            lacc = MFMA8(AFB(sh_d2, 3), w3r[1].y, lacc);
            lacc = MFMA8(AFB(sh_d2, 4), w3r[2].x, lacc);
            lacc = MFMA8(AFB(sh_d2, 5), w3r[2].y, lacc);
            lacc = MFMA8(AFB(sh_d2, 6), w3r[3].x, lacc);
            lacc = MFMA8(AFB(sh_d2, 7), w3r[3].y, lacc);
            const int col = w * 16 + l16;
            if (col < YDIM) {
                const float e0 = lacc[0] + s3r - tg0;
                const float e1 = lacc[1] + s3r - tg1;
                const float e2 = lacc[2] + s3r - tg2;
                const float e3 = lacc[3] + s3r - tg3;
                loss += e0 * e0 + e1 * e1 + e2 * e2 + e3 * e3;
            }
        }
        if (tid < BS * YDIM) sh_x[xr][xc] = f2f8(xv);
        BARX();                                  // publish x(t+1)
    }

    asm volatile("s_waitcnt vmcnt(0)" ::: "memory");
    #pragma unroll
    for (int s = 32; s > 0; s >>= 1) loss += __shfl_down(loss, s, 64);
    if (lane == 0 && w < 2) atomicAdd(out, loss);
}

extern "C" void kernel_launch(void* const* d_in, const int* in_sizes, int n_in,
                              void* d_out, int out_size, void* d_ws, size_t ws_size,
                              hipStream_t stream) {
    const float* data = (const float*)d_in[0];
    const float* Wih0 = (const float*)d_in[1];
    const float* Whh0 = (const float*)d_in[2];
    const float* bih0 = (const float*)d_in[3];
    const float* bhh0 = (const float*)d_in[4];
    const float* Wih1 = (const float*)d_in[5];
    const float* Whh1 = (const float*)d_in[6];
    const float* bih1 = (const float*)d_in[7];
    const float* bhh1 = (const float*)d_in[8];
    const float* W1   = (const float*)d_in[9];
    const float* b1   = (const float*)d_in[10];
    const float* W2   = (const float*)d_in[11];
    const float* b2   = (const float*)d_in[12];
    const float* W3   = (const float*)d_in[13];
    const float* b3   = (const float*)d_in[14];
    u16*   ws  = (u16*)d_ws;
    float* out = (float*)d_out;

    hipLaunchKernelGGL(prep_kernel, dim3(512), dim3(256), 0, stream,
                       Wih0, Whh0, Wih1, Whh1, W1, W2, W3, ws, out);
    hipLaunchKernelGGL(rnn_main, dim3(NWG), dim3(512), 0, stream,
                       data, bih0, bhh0, bih1, bhh1, b1, b2, b3, ws, out);
}

// Round 13
// 2119.955 us; speedup vs baseline: 1.3272x; 1.3272x over previous
//
#include <hip/hip_runtime.h>
#include <stdint.h>

typedef __attribute__((ext_vector_type(4))) float f32x4;
typedef __attribute__((ext_vector_type(2))) long lx2;
typedef unsigned short u16;
typedef unsigned char u8;

#define MFMA8(a,b,c) __builtin_amdgcn_mfma_f32_16x16x32_fp8_fp8((a),(b),(c),0,0,0)

static constexpr int T_STEPS = 256;
static constexpr int BATCH   = 2048;
static constexpr int YDIM    = 20;
static constexpr int BS      = 16;
static constexpr int NWG     = BATCH / BS;        // 128

// fp8 ws layout IDENTICAL to R10/R11 (proven, absmax 0): 768 pairs x 1KB = 24
// chunks x 32KB. Pair P, lane L, half h, j: byte P*1024+L*16+h*8+j = W[row][k],
// k = kb*32 + (L>>4)*8 + j. Consuming wave = P mod 8.
// R13: chunks 0-2 (whh0 kb0-3, 96KB) LDS-resident; chunks 3..23 streamed (672KB/step).
static constexpr int NPAIR   = 768;
static constexpr int WS_U16  = NPAIR * 512;       // 768 KB

__device__ __forceinline__ float sigm(float x) { return 1.0f / (1.0f + __expf(-x)); }
__device__ __forceinline__ float tanh_fast(float x) {
    float s = __expf(-2.0f * fabsf(x));
    float r = (1.0f - s) / (1.0f + s);
    return copysignf(r, x);
}
__device__ __forceinline__ f32x4 zero4() { f32x4 v = {0.f,0.f,0.f,0.f}; return v; }
__device__ __forceinline__ u8 f2f8(float v) {
    return (u8)(__builtin_amdgcn_cvt_pk_fp8_f32(v, v, 0, false) & 0xff);
}

__device__ float sval(int P, int half, int l16, int k8,
                      const float* __restrict__ Wih0, const float* __restrict__ Whh0,
                      const float* __restrict__ Wih1, const float* __restrict__ Whh1,
                      const float* __restrict__ W1,   const float* __restrict__ W2,
                      const float* __restrict__ W3) {
    if (P < 192) { int kb=P/24, r=P%24, g=r>>3, wv=r&7, c=wv+8*half;
        return Whh0[(g*256 + c*16 + l16)*256 + kb*32 + k8]; }
    if (P < 224) { int r=P-192; if (r>=24) return 0.f;
        int g=r>>3, wv=r&7, c=wv+8*half, row=g*256+c*16+l16;
        return (k8 < YDIM) ? Wih0[row*YDIM + k8] : 0.f; }
    if (P < 416) { int r=P-224, kb=r/24, rr=r%24, g=rr>>3, wv=rr&7, c=wv+8*half;
        return Whh1[(g*256 + c*16 + l16)*256 + kb*32 + k8]; }
    if (P < 608) { int r=P-416, kb=r/24, rr=r%24, g=rr>>3, wv=rr&7, c=wv+8*half;
        return Wih1[(g*256 + c*16 + l16)*256 + kb*32 + k8]; }
    if (P < 672) { int r=P-608, kb=r>>3, wv=r&7, row=(wv+8*half)*16+l16;
        return W1[row*256 + kb*32 + k8]; }
    if (P < 736) { int r=P-672, kb=r>>3, wv=r&7, row=(wv+8*half)*16+l16;
        return W2[row*256 + kb*32 + k8]; }
    { int r=P-736, s=r>>3, wv=r&7;
      if (wv < 2) { int kb = 2*s + half, row = wv*16 + l16;
          return (row < YDIM) ? W3[row*256 + kb*32 + k8] : 0.f; }
      return 0.f; }
}

__global__ void prep_kernel(const float* __restrict__ Wih0, const float* __restrict__ Whh0,
                            const float* __restrict__ Wih1, const float* __restrict__ Whh1,
                            const float* __restrict__ W1,   const float* __restrict__ W2,
                            const float* __restrict__ W3,   u16* __restrict__ ws,
                            float* __restrict__ out) {
    int tid = blockIdx.x * blockDim.x + threadIdx.x;
    if (tid == 0) out[0] = 0.0f;
    int stride = gridDim.x * blockDim.x;
    for (int m = tid; m < WS_U16; m += stride) {
        int byte0 = 2 * m;
        int P = byte0 >> 10, rem = byte0 & 1023;
        int L = rem >> 4, half = (rem >> 3) & 1, j0 = rem & 7;
        int l16 = L & 15, kqb = (L >> 4) * 8;
        float v0 = sval(P, half, l16, kqb + j0,     Wih0, Whh0, Wih1, Whh1, W1, W2, W3);
        float v1 = sval(P, half, l16, kqb + j0 + 1, Wih0, Whh0, Wih1, Whh1, W1, W2, W3);
        ws[m] = (u16)(__builtin_amdgcn_cvt_pk_fp8_f32(v0, v1, 0, false) & 0xffff);
    }
}

#define BARX() do {                                                 \
    asm volatile("s_waitcnt lgkmcnt(0)" ::: "memory");              \
    __builtin_amdgcn_sched_barrier(0);                              \
    __builtin_amdgcn_s_barrier();                                   \
    __builtin_amdgcn_sched_barrier(0);                              \
} while (0)

#define GM2(ACC, A, PV) do { ACC[0] = MFMA8((A), (PV).x, ACC[0]);   \
                             ACC[1] = MFMA8((A), (PV).y, ACC[1]); } while (0)
#define AFB(S, KT) (*(const long*)&(S)[l16][(KT) * 32 + kq8])
#define LOADC(R0, R1, R2, R3, C) do {                               \
    const u8* b_ = wsl + (size_t)(C) * 32768 + woff;                \
    R0 = *(const lx2*)(b_);          R1 = *(const lx2*)(b_ + 8192); \
    R2 = *(const lx2*)(b_ + 16384); R3 = *(const lx2*)(b_ + 24576); \
} while (0)
#define LP(BASE, P) (*(const lx2*)&(BASE)[(size_t)(P) * 1024 + (size_t)lane * 16])
#define XCH_A(P0,P1,P2,P3, S, KB, AR,AZ,AN) do {                    \
    const long a0_ = AFB(S, KB), a1_ = AFB(S, (KB)+1);              \
    GM2(AR,a0_,P0); GM2(AZ,a0_,P1); GM2(AN,a0_,P2); GM2(AR,a1_,P3); } while (0)
#define XCH_B(P0,P1,P2,P3, S, KB, AR,AZ,AN) do {                    \
    const long a0_ = AFB(S, KB), a1_ = AFB(S, (KB)+1);              \
    GM2(AZ,a0_,P0); GM2(AN,a0_,P1); GM2(AR,a1_,P2); GM2(AZ,a1_,P3); } while (0)
#define XCH_C(P0,P1,P2,P3, S, KB, AR,AZ,AN) do {                    \
    const long a0_ = AFB(S, KB), a1_ = AFB(S, (KB)+1);              \
    GM2(AN,a0_,P0); GM2(AR,a1_,P1); GM2(AZ,a1_,P2); GM2(AN,a1_,P3); } while (0)
#define XCH_M(P0,P1,P2,P3, S, KB0) do {                             \
    const long m0_ = AFB(S, KB0),     m1_ = AFB(S, (KB0)+1);        \
    const long m2_ = AFB(S, (KB0)+2), m3_ = AFB(S, (KB0)+3);        \
    d0 = MFMA8(m0_, P0.x, d0);  d1v = MFMA8(m0_, P0.y, d1v);        \
    d0 = MFMA8(m1_, P1.x, d0);  d1v = MFMA8(m1_, P1.y, d1v);        \
    d0 = MFMA8(m2_, P2.x, d0);  d1v = MFMA8(m2_, P2.y, d1v);        \
    d0 = MFMA8(m3_, P3.x, d0);  d1v = MFMA8(m3_, P3.y, d1v);        \
} while (0)
#define COMBINE(HSH, HR, BRv, BZv, BXNv, BHNv, AR, AZ, AXN, AHN) do {            \
    _Pragma("unroll") for (int jj = 0; jj < 2; ++jj) {                           \
        const int colb_ = (w + 8 * jj) * 16 + l16;                               \
        _Pragma("unroll") for (int q = 0; q < 4; ++q) {                          \
            const float r_ = sigm(AR[jj][q] + BRv[jj]);                          \
            const float z_ = sigm(AZ[jj][q] + BZv[jj]);                          \
            const float n_ = tanh_fast(AXN[jj][q] + BXNv[jj] + r_ * (AHN[jj][q] + BHNv[jj])); \
            const float hn_ = (1.0f - z_) * n_ + z_ * HR[jj][q];                 \
            HR[jj][q] = hn_;                                                     \
            HSH[kq * 4 + q][colb_] = f2f8(hn_); } }                              \
} while (0)
#define DWRITE(DSH, SB) do {                                                     \
    _Pragma("unroll") for (int q = 0; q < 4; ++q) {                              \
        DSH[kq * 4 + q][w * 16 + l16]       = f2f8(fmaxf(d0[q]  + SB[0], 0.f));  \
        DSH[kq * 4 + q][(8 + w) * 16 + l16] = f2f8(fmaxf(d1v[q] + SB[1], 0.f)); }\
} while (0)
#define ZACC(A) do { A[0] = zero4(); A[1] = zero4(); } while (0)

__global__ __launch_bounds__(512, 1) void rnn_main(
    const float* __restrict__ data,
    const float* __restrict__ bih0g, const float* __restrict__ bhh0g,
    const float* __restrict__ bih1g, const float* __restrict__ bhh1g,
    const float* __restrict__ b1g,  const float* __restrict__ b2g,
    const float* __restrict__ b3g,
    const u16* __restrict__ ws, float* __restrict__ out)
{
    __shared__ __align__(16) u8 lds_whh0[3 * 32768];  // chunks 0-2 (whh0 kb0-3), resident
    __shared__ __align__(16) u8 sh_h0[2][16][272];
    __shared__ __align__(16) u8 sh_h1[2][16][272];
    __shared__ __align__(16) u8 sh_d1[16][272];
    __shared__ __align__(16) u8 sh_d2[16][272];
    __shared__ __align__(16) u8 sh_x[16][32];

    const int tid  = threadIdx.x;
    const int w    = tid >> 6;
    const int lane = tid & 63;
    const int l16  = lane & 15;
    const int kq   = lane >> 4;
    const int kq8  = kq * 8;
    const int b0   = blockIdx.x * BS;
    const int xr   = tid / YDIM, xc = tid - xr * YDIM;
    const size_t woff = (size_t)w * 1024 + (size_t)lane * 16;

    // one-time: chunks 0-2 -> LDS
    {
        const lx2* s = (const lx2*)ws;
        lx2* dW = (lx2*)lds_whh0;
        for (int i = tid; i < 6144; i += 512) dW[i] = s[i];
    }

    for (int i = tid; i < 2 * 16 * 272; i += 512) { (&sh_h0[0][0][0])[i] = 0; (&sh_h1[0][0][0])[i] = 0; }
    for (int i = tid; i < 16 * 32;  i += 512) (&sh_x[0][0])[i] = 0;
    if (tid < BS * YDIM) sh_x[xr][xc] = f2f8(data[(size_t)b0 * YDIM + tid]);

    float bR0[2], bZ0[2], bXN0[2], bHN0[2], bR1[2], bZ1[2], bXN1[2], bHN1[2], s1r[2], s2r[2];
    #pragma unroll
    for (int jj = 0; jj < 2; ++jj) {
        const int colb = (w + 8 * jj) * 16 + l16;
        bR0[jj]  = bih0g[colb] + bhh0g[colb];
        bZ0[jj]  = bih0g[colb + 256] + bhh0g[colb + 256];
        bXN0[jj] = bih0g[colb + 512];  bHN0[jj] = bhh0g[colb + 512];
        bR1[jj]  = bih1g[colb] + bhh1g[colb];
        bZ1[jj]  = bih1g[colb + 256] + bhh1g[colb + 256];
        bXN1[jj] = bih1g[colb + 512];  bHN1[jj] = bhh1g[colb + 512];
        s1r[jj]  = b1g[colb];  s2r[jj] = b2g[colb];
    }
    float s3r = 0.0f;
    { const int col = w * 16 + l16; if (w < 2 && col < YDIM) s3r = b3g[col]; }

    float hr0[2][4] = {{0,0,0,0},{0,0,0,0}};
    float hr1[2][4] = {{0,0,0,0},{0,0,0,0}};
    f32x4 r0[2], z0[2], xn0[2], hn0[2];
    f32x4 r1[2], z1[2], xn1[2], hn1[2];
    f32x4 d0, d1v;
    lx2 p00, p01, p02, p03, p10, p11, p12, p13, p20, p21, p22, p23;

    __syncthreads();   // LDS residents + state ready

    {   // prologue: prime 3-deep ring with chunks 3,4,5
        const u8* wsl = (const u8*)ws;
        LOADC(p00, p01, p02, p03, 3);
        LOADC(p10, p11, p12, p13, 4);
        LOADC(p20, p21, p22, p23, 5);
    }
    float loss = 0.0f;

    #pragma unroll 1
    for (int t = 0; t < T_STEPS - 1; ++t) {
        const u8* wsl = (const u8*)ws;
        asm volatile("" : "+s"(wsl));     // defeat LICM on stream loads
        u8 (*h0o)[272] = sh_h0[t & 1];  u8 (*h0n)[272] = sh_h0[(t & 1) ^ 1];
        u8 (*h1o)[272] = sh_h1[t & 1];  u8 (*h1n)[272] = sh_h1[(t & 1) ^ 1];

        ZACC(r0); ZACC(z0); ZACC(xn0); ZACC(hn0);
        ZACC(r1); ZACC(z1); ZACC(xn1); ZACC(hn1);

        // ===== Phase A: gh0 (kb0-3 LDS, kb4-7 stream) + gx0 (stream) + gh1 (stream) =====
        {   lx2 q0=LP(lds_whh0, w),    q1=LP(lds_whh0, 8+w),  q2=LP(lds_whh0, 16+w), q3=LP(lds_whh0, 24+w);
            XCH_A(q0,q1,q2,q3, h0o, 0, r0,z0,hn0); }
        {   lx2 q0=LP(lds_whh0, 32+w), q1=LP(lds_whh0, 40+w), q2=LP(lds_whh0, 48+w), q3=LP(lds_whh0, 56+w);
            XCH_B(q0,q1,q2,q3, h0o, 1, r0,z0,hn0); }
        {   lx2 q0=LP(lds_whh0, 64+w), q1=LP(lds_whh0, 72+w), q2=LP(lds_whh0, 80+w), q3=LP(lds_whh0, 88+w);
            XCH_C(q0,q1,q2,q3, h0o, 2, r0,z0,hn0); }
        XCH_A(p00,p01,p02,p03, h0o, 4, r0,z0,hn0);  LOADC(p00,p01,p02,p03, 6);
        XCH_B(p10,p11,p12,p13, h0o, 5, r0,z0,hn0);  LOADC(p10,p11,p12,p13, 7);
        XCH_C(p20,p21,p22,p23, h0o, 6, r0,z0,hn0);  LOADC(p20,p21,p22,p23, 8);
        {   // gx0 (chunk 6: 3 pairs used)
            const long ax = *(const long*)&sh_x[l16][kq8];
            GM2(r0, ax, p00); GM2(z0, ax, p01); GM2(xn0, ax, p02);
        }
        LOADC(p00,p01,p02,p03, 9);
        XCH_A(p10,p11,p12,p13, h1o, 0, r1,z1,hn1);  LOADC(p10,p11,p12,p13, 10);
        XCH_B(p20,p21,p22,p23, h1o, 1, r1,z1,hn1);  LOADC(p20,p21,p22,p23, 11);
        XCH_C(p00,p01,p02,p03, h1o, 2, r1,z1,hn1);  LOADC(p00,p01,p02,p03, 12);
        XCH_A(p10,p11,p12,p13, h1o, 4, r1,z1,hn1);  LOADC(p10,p11,p12,p13, 13);
        XCH_B(p20,p21,p22,p23, h1o, 5, r1,z1,hn1);  LOADC(p20,p21,p22,p23, 14);
        XCH_C(p00,p01,p02,p03, h1o, 6, r1,z1,hn1);  LOADC(p00,p01,p02,p03, 15);
        COMBINE(h0n, hr0, bR0, bZ0, bXN0, bHN0, r0, z0, xn0, hn0);
        BARX();                                  // B2: publish h0new
        // ===== Phase C: gx1 = wih1 @ h0new (stream c13-18) =====
        XCH_A(p10,p11,p12,p13, h0n, 0, r1,z1,xn1);  LOADC(p10,p11,p12,p13, 16);
        XCH_B(p20,p21,p22,p23, h0n, 1, r1,z1,xn1);  LOADC(p20,p21,p22,p23, 17);
        XCH_C(p00,p01,p02,p03, h0n, 2, r1,z1,xn1);  LOADC(p00,p01,p02,p03, 18);
        XCH_A(p10,p11,p12,p13, h0n, 4, r1,z1,xn1);  LOADC(p10,p11,p12,p13, 19);
        XCH_B(p20,p21,p22,p23, h0n, 5, r1,z1,xn1);  LOADC(p20,p21,p22,p23, 20);
        XCH_C(p00,p01,p02,p03, h0n, 6, r1,z1,xn1);  LOADC(p00,p01,p02,p03, 21);
        COMBINE(h1n, hr1, bR1, bZ1, bXN1, bHN1, r1, z1, xn1, hn1);
        BARX();                                  // B3: publish h1new
        // ===== Phase D: W1 (stream c19,c20); x(t+1)/targets; stage x; d1 =====
        d0 = zero4(); d1v = zero4();
        float xv = 0.f, tg0 = 0.f, tg1 = 0.f, tg2 = 0.f, tg3 = 0.f;
        {
            const float* tp = data + (size_t)(t + 1) * (BATCH * YDIM) + (size_t)b0 * YDIM;
            if (tid < BS * YDIM) xv = tp[tid];
            if (w < 2) {
                const int col = w * 16 + l16;
                if (col < YDIM) {
                    tg0 = tp[(kq * 4 + 0) * YDIM + col];
                    tg1 = tp[(kq * 4 + 1) * YDIM + col];
                    tg2 = tp[(kq * 4 + 2) * YDIM + col];
                    tg3 = tp[(kq * 4 + 3) * YDIM + col];
                }
            }
        }
        XCH_M(p10,p11,p12,p13, h1n, 0);  LOADC(p10,p11,p12,p13, 22);
        XCH_M(p20,p21,p22,p23, h1n, 4);  LOADC(p20,p21,p22,p23, 23);
        DWRITE(sh_d1, s1r);
        if (tid < BS * YDIM) sh_x[xr][xc] = f2f8(xv);   // safe: all waves past phase-A x reads
        BARX();                                  // B4: publish d1 + x(t+1)
        // ===== Phase E: W2 (stream c21,c22) =====
        d0 = zero4(); d1v = zero4();
        XCH_M(p00,p01,p02,p03, sh_d1, 0);  LOADC(p00,p01,p02,p03, 3);
        XCH_M(p10,p11,p12,p13, sh_d1, 4);  LOADC(p10,p11,p12,p13, 4);
        DWRITE(sh_d2, s2r);
        BARX();                                  // B5: publish d2
        // ===== Phase F: W3 + loss (waves 0,1; stream c23); no trailing barrier =====
        if (w < 2) {
            f32x4 lacc = zero4();
            lacc = MFMA8(AFB(sh_d2, 0), p20.x, lacc);
            lacc = MFMA8(AFB(sh_d2, 1), p20.y, lacc);
            lacc = MFMA8(AFB(sh_d2, 2), p21.x, lacc);
            lacc = MFMA8(AFB(sh_d2, 3), p21.y, lacc);
            lacc = MFMA8(AFB(sh_d2, 4), p22.x, lacc);
            lacc = MFMA8(AFB(sh_d2, 5), p22.y, lacc);
            lacc = MFMA8(AFB(sh_d2, 6), p23.x, lacc);
            lacc = MFMA8(AFB(sh_d2, 7), p23.y, lacc);
            const int col = w * 16 + l16;
            if (col < YDIM) {
                const float e0 = lacc[0] + s3r - tg0;
                const float e1 = lacc[1] + s3r - tg1;
                const float e2 = lacc[2] + s3r - tg2;
                const float e3 = lacc[3] + s3r - tg3;
                loss += e0 * e0 + e1 * e1 + e2 * e2 + e3 * e3;
            }
        }
        LOADC(p20,p21,p22,p23, 5);               // all waves (next step's c5)
        // cross-step safety: first shared write of step t+1 (COMBINE->h0n) is
        // behind B2(t+1), which blocks until waves 0,1 finish phase F.
    }

    asm volatile("s_waitcnt vmcnt(0)" ::: "memory");
    #pragma unroll
    for (int s = 32; s > 0; s >>= 1) loss += __shfl_down(loss, s, 64);
    if (lane == 0 && w < 2) atomicAdd(out, loss);
}

extern "C" void kernel_launch(void* const* d_in, const int* in_sizes, int n_in,
                              void* d_out, int out_size, void* d_ws, size_t ws_size,
                              hipStream_t stream) {
    const float* data = (const float*)d_in[0];
    const float* Wih0 = (const float*)d_in[1];
    const float* Whh0 = (const float*)d_in[2];
    const float* bih0 = (const float*)d_in[3];
    const float* bhh0 = (const float*)d_in[4];
    const float* Wih1 = (const float*)d_in[5];
    const float* Whh1 = (const float*)d_in[6];
    const float* bih1 = (const float*)d_in[7];
    const float* bhh1 = (const float*)d_in[8];
    const float* W1   = (const float*)d_in[9];
    const float* b1   = (const float*)d_in[10];
    const float* W2   = (const float*)d_in[11];
    const float* b2   = (const float*)d_in[12];
    const float* W3   = (const float*)d_in[13];
    const float* b3   = (const float*)d_in[14];
    u16*   ws  = (u16*)d_ws;
    float* out = (float*)d_out;

    hipLaunchKernelGGL(prep_kernel, dim3(512), dim3(256), 0, stream,
                       Wih0, Whh0, Wih1, Whh1, W1, W2, W3, ws, out);
    hipLaunchKernelGGL(rnn_main, dim3(NWG), dim3(512), 0, stream,
                       data, bih0, bhh0, bih1, bhh1, b1, b2, b3, ws, out);
}